// Round 9
// baseline (298.053 us; speedup 1.0000x reference)
//
#include <hip/hip_runtime.h>
#include <hip/hip_bf16.h>
#include <stdint.h>

// HaloWindowAttention: B=512,C=128,H=W=16, WSH=24 -> 1 window/batch, 576 tokens,
// 4 heads x 32 dim, q = flat tokens [100,356), out [B,C,16,16] f32.
//
// Round-8 restructure: qkv+attn FUSED, one block per batch, K/V/Q never touch
// HBM (were 185 MB written + 182 MB re-read = the round-7 bottleneck).
// ws (u16): wp[16384] | wq[49152] | ao[512*256*128]  (~33.7 MB)

typedef short bf16x8 __attribute__((ext_vector_type(8)));
typedef float f32x4 __attribute__((ext_vector_type(4)));

__device__ __forceinline__ unsigned short f2bf(float f) {
  unsigned int u = __builtin_bit_cast(unsigned int, f);
  u += 0x7fffu + ((u >> 16) & 1u);
  return (unsigned short)(u >> 16);
}

__device__ __forceinline__ unsigned int cvt_pk_bf16(float lo, float hi) {
  unsigned int r;
  asm("v_cvt_pk_bf16_f32 %0, %1, %2" : "=v"(r) : "v"(lo), "v"(hi));
  return r;
}

__device__ __forceinline__ f32x4 mfma_16x16x32(bf16x8 a, bf16x8 b, f32x4 c) {
  return __builtin_amdgcn_mfma_f32_16x16x32_bf16(a, b, c, 0, 0, 0);
}

// LDS-only barrier (no vmcnt drain; cross-wave comms here are LDS-only).
__device__ __forceinline__ void bar_lds() {
  asm volatile("s_waitcnt lgkmcnt(0)\n\ts_barrier" ::: "memory");
}

// ---------------- kernel 0: weights f32 -> bf16 ----------------
__global__ void wcvt(const float* __restrict__ qkv_w, const float* __restrict__ proj_w,
                     unsigned short* __restrict__ wq, unsigned short* __restrict__ wp) {
  int i = blockIdx.x * 256 + threadIdx.x;
  if (i < 49152) wq[i] = f2bf(qkv_w[i]);
  if (i < 16384) wp[i] = f2bf(proj_w[i]);
}

// ---------------- kernel 1: FUSED reflect-gather + QKV + flash attention ----------------
// grid = 512 (one block per batch), block = 512 (8 waves).
// LDS: XS 64K (x staged, whole kernel) | QC 20K | KF 36K | VT 36.5K = 160,256 B.
// Per head: GEMM phase (216 16x16 frag-tiles over 8 waves, outputs written
// straight into attn-consumable LDS layouts) -> attn phase (full 576 kv in
// LDS, swapped-QK zero-shuffle pipeline, 32 q-rows/wave).
__global__ __launch_bounds__(512) void fused_kernel(
    const float* __restrict__ x, const unsigned short* __restrict__ wq,
    const float* __restrict__ qkv_b, unsigned short* __restrict__ ao) {
  __shared__ __align__(16) unsigned int XS[256 * 64];        // [s][cdw ^ ((s&7)<<2)]
  __shared__ __align__(16) unsigned short QC[256 * 40];      // [qi][d] pad-40
  __shared__ __align__(16) unsigned short KFS[4 * 576 * 8];  // [g][kv][j] (B-frag layout)
  __shared__ __align__(16) unsigned short VT[32 * 584];      // [d][kv-phys] stride 584
  const int b = blockIdx.x;
  const int tid = threadIdx.x;
  const int lane = tid & 63;
  const int wid = tid >> 6;        // 0..7
  const int g = lane >> 4;
  const int r16 = lane & 15;

  const float* xb = x + (size_t)b * 32768;

  // --- phase 0: stage x[b] -> XS (coalesced, swizzled) ---
  {
    int s = tid & 255;
    int half = tid >> 8;
    #pragma unroll 4
    for (int it = 0; it < 32; ++it) {
      int cp = half * 32 + it;
      float f0 = xb[(2 * cp) * 256 + s];
      float f1 = xb[(2 * cp + 1) * 256 + s];
      XS[s * 64 + (cp ^ ((s & 7) << 2))] =
          (unsigned int)f2bf(f0) | ((unsigned int)f2bf(f1) << 16);
    }
  }

  const float KE = 0.17677669529663687f * 1.4426950408889634f;  // SCALE*log2(e)

  for (int h = 0; h < 4; ++h) {
    bar_lds();  // phase-0 staging visible / previous head's attn reads done

    // --- GEMM phase: 576 tok x 96 n (q,k,v of head h), K=128 ---
    for (int i = 0; i < 27; ++i) {
      int idx = i * 8 + wid;          // 0..215
      int mt = idx / 6, nt = idx - mt * 6;
      int sel = nt >> 1;              // 0=q 1=k 2=v
      int dcol = (nt & 1) * 16 + r16; // 0..31 within head
      int n_abs = sel * 128 + h * 32 + dcol;
      float bv = qkv_b[n_abs];
      // reflect map for A rows (token = mt*16 + r16)
      int tg = mt * 16 + r16;
      int ph = tg / 24;
      int pw = tg - ph * 24;
      int hh = ph - 4; hh = (hh < 0) ? -hh : ((hh > 15) ? 30 - hh : hh);
      int wc = pw - 4; wc = (wc < 0) ? -wc : ((wc > 15) ? 30 - wc : wc);
      int sv = hh * 16 + wc;
      f32x4 acc = f32x4{0.f, 0.f, 0.f, 0.f};
      #pragma unroll
      for (int kt = 0; kt < 4; ++kt) {
        bf16x8 afr = __builtin_bit_cast(
            bf16x8, *(const uint4*)&XS[sv * 64 + ((kt * 16 + g * 4) ^ ((sv & 7) << 2))]);
        bf16x8 bfr = __builtin_bit_cast(
            bf16x8, *(const uint4*)(wq + n_abs * 128 + kt * 32 + g * 8));
        acc = mfma_16x16x32(afr, bfr, acc);
      }
      // D: lane (g,r16): col n = dcol, rows tok = mt*16 + 4g + rr
      #pragma unroll
      for (int rr = 0; rr < 4; ++rr) {
        int tok = mt * 16 + 4 * g + rr;
        unsigned short val = f2bf(acc[rr] + bv);
        if (sel == 0) {
          int qi = tok - 100;
          if ((unsigned)qi < 256u) QC[qi * 40 + dcol] = val;
        } else if (sel == 1) {
          KFS[(dcol >> 3) * 4608 + tok * 8 + (dcol & 7)] = val;
        } else {
          int phv = (tok >> 5) * 32 + ((tok & 15) >> 2) * 8 + ((tok >> 4) & 1) * 4 + (tok & 3);
          VT[dcol * 584 + phv] = val;
        }
      }
    }
    bar_lds();  // q/k/v visible to all waves

    // --- attn phase: 32 q-rows per wave, full 576 kv in LDS ---
    const int qb = wid * 32;
    bf16x8 qf[2];
    #pragma unroll
    for (int qnt = 0; qnt < 2; ++qnt)
      qf[qnt] = __builtin_bit_cast(bf16x8, *(const uint4*)&QC[(qb + qnt * 16 + r16) * 40 + g * 8]);

    float ls[2] = {0.f, 0.f};
    f32x4 oa[2][2];
    #pragma unroll
    for (int i2 = 0; i2 < 2; ++i2)
      #pragma unroll
      for (int j2 = 0; j2 < 2; ++j2) oa[i2][j2] = f32x4{0.f, 0.f, 0.f, 0.f};

    for (int kvt2 = 0; kvt2 < 18; ++kvt2) {
      bf16x8 kf0 = __builtin_bit_cast(bf16x8, *(const uint4*)&KFS[g * 4608 + (kvt2 * 32 + r16) * 8]);
      bf16x8 kf1 = __builtin_bit_cast(bf16x8, *(const uint4*)&KFS[g * 4608 + (kvt2 * 32 + 16 + r16) * 8]);
      f32x4 zero = f32x4{0.f, 0.f, 0.f, 0.f};
      bf16x8 pf[2];
      #pragma unroll
      for (int qnt = 0; qnt < 2; ++qnt) {
        f32x4 s0 = mfma_16x16x32(kf0, qf[qnt], zero);
        f32x4 s1 = mfma_16x16x32(kf1, qf[qnt], zero);
        float p[8];
        #pragma unroll
        for (int j = 0; j < 4; ++j) p[j] = __builtin_amdgcn_exp2f(s0[j] * KE);
        #pragma unroll
        for (int j = 0; j < 4; ++j) p[4 + j] = __builtin_amdgcn_exp2f(s1[j] * KE);
        ls[qnt] += ((p[0] + p[1]) + (p[2] + p[3])) + ((p[4] + p[5]) + (p[6] + p[7]));
        uint4 pk4;
        pk4.x = cvt_pk_bf16(p[0], p[1]);
        pk4.y = cvt_pk_bf16(p[2], p[3]);
        pk4.z = cvt_pk_bf16(p[4], p[5]);
        pk4.w = cvt_pk_bf16(p[6], p[7]);
        pf[qnt] = __builtin_bit_cast(bf16x8, pk4);
      }
      #pragma unroll
      for (int dmt = 0; dmt < 2; ++dmt) {
        int d = dmt * 16 + r16;
        bf16x8 vf = __builtin_bit_cast(bf16x8, *(const uint4*)&VT[d * 584 + kvt2 * 32 + g * 8]);
        #pragma unroll
        for (int qnt = 0; qnt < 2; ++qnt)
          oa[dmt][qnt] = mfma_16x16x32(vf, pf[qnt], oa[dmt][qnt]);
      }
    }

    // epilogue: normalize + write ao (token-major [b][q][128])
    #pragma unroll
    for (int qnt = 0; qnt < 2; ++qnt) {
      float l = ls[qnt];
      l += __shfl_xor(l, 16);
      l += __shfl_xor(l, 32);
      float rl = 1.0f / l;
      int q = qb + qnt * 16 + r16;
      #pragma unroll
      for (int dmt = 0; dmt < 2; ++dmt) {
        #pragma unroll
        for (int rr = 0; rr < 4; ++rr) {
          int d = dmt * 16 + 4 * g + rr;
          ao[((size_t)b * 256 + q) * 128 + h * 32 + d] = f2bf(oa[dmt][qnt][rr] * rl);
        }
      }
    }
  }
}

// ---------------- kernel 2: output projection + layout to [B,C,16,16] ----------------
__global__ __launch_bounds__(256) void proj_kernel(
    const unsigned short* __restrict__ ao, const unsigned short* __restrict__ wp,
    const float* __restrict__ proj_b, float* __restrict__ out) {
  __shared__ __align__(16) unsigned int A32[64 * 64];
  const int wg = blockIdx.x;
  const int b = wg >> 2;
  const int mq = wg & 3;
  const int tid = threadIdx.x;
  const int lane = tid & 63;
  const int wid = tid >> 6;
  const int g = lane >> 4;
  const int r16 = lane & 15;

  const unsigned int* asrc = (const unsigned int*)(ao + ((size_t)b * 256 + mq * 64) * 128);
  #pragma unroll
  for (int it = 0; it < 4; ++it) {
    int f = it * 256 + tid;
    int row = f >> 4, q4 = f & 15;
    uint4 v = *(const uint4*)&asrc[row * 64 + q4 * 4];
    *(uint4*)&A32[row * 64 + ((q4 * 4) ^ ((row & 7) << 2))] = v;
  }
  bar_lds();

  f32x4 acc[2][4];
  #pragma unroll
  for (int nt = 0; nt < 2; ++nt)
    #pragma unroll
    for (int mt = 0; mt < 4; ++mt) acc[nt][mt] = f32x4{0.f, 0.f, 0.f, 0.f};

  for (int kt = 0; kt < 4; ++kt) {
    bf16x8 afr[4];
    #pragma unroll
    for (int mt = 0; mt < 4; ++mt) {
      int row = mt * 16 + r16;
      int cub = (kt * 16 + g * 4) ^ ((row & 7) << 2);
      afr[mt] = __builtin_bit_cast(bf16x8, *(const uint4*)&A32[row * 64 + cub]);
    }
    #pragma unroll
    for (int nt = 0; nt < 2; ++nt) {
      int n = wid * 32 + nt * 16 + r16;
      bf16x8 bfr = __builtin_bit_cast(bf16x8, *(const uint4*)(wp + n * 128 + kt * 32 + g * 8));
      #pragma unroll
      for (int mt = 0; mt < 4; ++mt)
        acc[nt][mt] = mfma_16x16x32(afr[mt], bfr, acc[nt][mt]);
    }
  }

  #pragma unroll
  for (int nt = 0; nt < 2; ++nt) {
    int c = wid * 32 + nt * 16 + r16;
    float bv = proj_b[c];
    #pragma unroll
    for (int mt = 0; mt < 4; ++mt) {
      int t0 = mq * 64 + mt * 16 + 4 * g;  // regs r0..r3 = 4 consecutive tokens
      float4 o;
      o.x = acc[nt][mt][0] + bv;
      o.y = acc[nt][mt][1] + bv;
      o.z = acc[nt][mt][2] + bv;
      o.w = acc[nt][mt][3] + bv;
      *(float4*)&out[((size_t)b * 128 + c) * 256 + t0] = o;
    }
  }
}

extern "C" void kernel_launch(void* const* d_in, const int* in_sizes, int n_in,
                              void* d_out, int out_size, void* d_ws, size_t ws_size,
                              hipStream_t stream) {
  const float* x = (const float*)d_in[0];
  const float* qkv_w = (const float*)d_in[1];
  const float* qkv_b = (const float*)d_in[2];
  const float* proj_w = (const float*)d_in[3];
  const float* proj_b = (const float*)d_in[4];
  float* out = (float*)d_out;

  unsigned short* ws16 = (unsigned short*)d_ws;
  unsigned short* wp = ws16;                       // 16,384
  unsigned short* wq = ws16 + 16384;               // 49,152
  unsigned short* ap = ws16 + 65536;               // 16,777,216
  // total ws requirement: ~33.7 MB

  hipLaunchKernelGGL(wcvt, dim3(192), dim3(256), 0, stream, qkv_w, proj_w, wq, wp);
  hipLaunchKernelGGL(fused_kernel, dim3(512), dim3(512), 0, stream, x, wq, qkv_b, ap);
  hipLaunchKernelGGL(proj_kernel, dim3(2048), dim3(256), 0, stream, ap, wp, proj_b, out);
}

// Round 13
// 260.435 us; speedup vs baseline: 1.1444x; 1.1444x over previous
//
#include <hip/hip_runtime.h>
#include <hip/hip_bf16.h>
#include <stdint.h>

// HaloWindowAttention: B=512,C=128,H=W=16, WSH=24 -> 1 window/batch, 576 tokens,
// 4 heads x 32 dim, q = flat tokens [100,356), out [B,C,16,16] f32.
//
// Round-13: R7-proven pipeline, with qkv fed by pre-transposed xT (global
// A-frags, per-(batch,tile) blocks, XCD-swizzled). Also a hardware bisect of
// the xt path for the fused-kernel debug (R10-R12).
// ws (u16): wp[16384] | wq[49152] | xt&ao-alias[16.8M] | qc[16.8M] |
//   kw[37.7M] | vw[37.7M]  = 218,234,880 B (proven budget).

typedef short bf16x8 __attribute__((ext_vector_type(8)));
typedef float f32x4 __attribute__((ext_vector_type(4)));

__device__ __forceinline__ unsigned short f2bf(float f) {
  unsigned int u = __builtin_bit_cast(unsigned int, f);
  u += 0x7fffu + ((u >> 16) & 1u);
  return (unsigned short)(u >> 16);
}

__device__ __forceinline__ unsigned int cvt_pk_bf16(float lo, float hi) {
  unsigned int r;
  asm("v_cvt_pk_bf16_f32 %0, %1, %2" : "=v"(r) : "v"(lo), "v"(hi));
  return r;
}

__device__ __forceinline__ f32x4 mfma_16x16x32(bf16x8 a, bf16x8 b, f32x4 c) {
  return __builtin_amdgcn_mfma_f32_16x16x32_bf16(a, b, c, 0, 0, 0);
}

// LDS-only barrier (R7-proven): no vmcnt drain; stores keep flying.
__device__ __forceinline__ void bar_lds() {
  asm volatile("s_waitcnt lgkmcnt(0)\n\ts_barrier" ::: "memory");
}

__device__ __forceinline__ int reflect_s(int tg) {
  int ph = tg / 24;
  int pw = tg - ph * 24;
  int hh = ph - 4; hh = (hh < 0) ? -hh : ((hh > 15) ? 30 - hh : hh);
  int wc = pw - 4; wc = (wc < 0) ? -wc : ((wc > 15) ? 30 - wc : wc);
  return hh * 16 + wc;
}

// ---------------- kernel 0: weights f32 -> bf16 ----------------
__global__ void wcvt(const float* __restrict__ qkv_w, const float* __restrict__ proj_w,
                     unsigned short* __restrict__ wq, unsigned short* __restrict__ wp) {
  int i = blockIdx.x * 256 + threadIdx.x;
  if (i < 49152) wq[i] = f2bf(qkv_w[i]);
  if (i < 16384) wp[i] = f2bf(proj_w[i]);
}

// ---------------- kernel 1: x [C][S] f32 -> xT [S][C] bf16 ----------------
__global__ __launch_bounds__(256) void xt_kernel(const float* __restrict__ x,
                                                 unsigned short* __restrict__ xt) {
  __shared__ __align__(16) unsigned int XS[256 * 64];
  const int b = blockIdx.x, tid = threadIdx.x;
  const float* xb = x + (size_t)b * 32768;
  #pragma unroll 4
  for (int it = 0; it < 64; ++it) {
    float f0 = xb[(2 * it) * 256 + tid];
    float f1 = xb[(2 * it + 1) * 256 + tid];
    XS[tid * 64 + (it ^ ((tid & 7) << 2))] =
        (unsigned int)f2bf(f0) | ((unsigned int)f2bf(f1) << 16);
  }
  bar_lds();
  unsigned int* xtd = (unsigned int*)xt + (size_t)b * 16384;  // 256 s * 64 dwords
  #pragma unroll
  for (int it = 0; it < 4; ++it) {
    int s = it * 64 + (tid >> 2);
    int cg = (tid & 3) * 4;
    #pragma unroll
    for (int m = 0; m < 4; ++m) {
      uint4 v = *(const uint4*)&XS[s * 64 + (((cg + m) ^ (s & 7)) << 2)];
      *(uint4*)&xtd[s * 64 + (cg + m) * 4] = v;
    }
  }
}

// ---------------- kernel 2: QKV GEMM per (batch, 64-token tile) ----------------
// grid = 4608, XCD-swizzled: logical = (bid&7)*576 + (bid>>3); b = logical/9,
// tile = logical%9 -> each XCD's L2 serves its own 64 batches (4 MB) of xt.
// A-frags direct from global xt (L2-hot); weights bf16 from wq (L2-hot).
// LDS = OB 16 KB only. Output transpose + uint4 stores as in R7 (proven).
__global__ __launch_bounds__(256) void qkv_kernel(
    const unsigned short* __restrict__ xt, const unsigned short* __restrict__ wq,
    const float* __restrict__ qkv_b, unsigned short* __restrict__ qc,
    unsigned short* __restrict__ kw, unsigned short* __restrict__ vw) {
  __shared__ __align__(16) unsigned short OB[64 * 128];
  const int bid = blockIdx.x;
  const int logical = (bid & 7) * 576 + (bid >> 3);
  const int b = logical / 9;
  const int tile = logical - b * 9;
  const int tid = threadIdx.x;
  const int lane = tid & 63;
  const int wid = tid >> 6;
  const int g = lane >> 4;
  const int r16 = lane & 15;

  const unsigned int* xtd = (const unsigned int*)xt + (size_t)b * 16384;

  // reflected spatial rows for this tile's 4 m-tiles (lane r16 = row in tile)
  int sv[4];
  #pragma unroll
  for (int mt = 0; mt < 4; ++mt)
    sv[mt] = reflect_s(tile * 64 + mt * 16 + r16);

  float bias[6];
  #pragma unroll
  for (int i = 0; i < 6; ++i) bias[i] = qkv_b[(wid + 4 * i) * 16 + r16];

  f32x4 acc[6][4];
  #pragma unroll
  for (int i = 0; i < 6; ++i)
    #pragma unroll
    for (int mt = 0; mt < 4; ++mt) acc[i][mt] = f32x4{0.f, 0.f, 0.f, 0.f};

  #pragma unroll
  for (int kt = 0; kt < 4; ++kt) {
    bf16x8 afr[4];
    #pragma unroll
    for (int mt = 0; mt < 4; ++mt)
      afr[mt] = __builtin_bit_cast(bf16x8, *(const uint4*)&xtd[sv[mt] * 64 + kt * 16 + g * 4]);
    #pragma unroll
    for (int i = 0; i < 6; ++i) {
      int n = (wid + 4 * i) * 16 + r16;   // interleaved n-tiles (R7-proven)
      bf16x8 bfr = __builtin_bit_cast(bf16x8, *(const uint4*)(wq + n * 128 + kt * 32 + g * 8));
      #pragma unroll
      for (int mt = 0; mt < 4; ++mt)
        acc[i][mt] = mfma_16x16x32(afr[mt], bfr, acc[i][mt]);
    }
  }

  #pragma unroll
  for (int sel = 0; sel < 3; ++sel) {
    bar_lds();  // prior sel's OB reads done (LDS only)
    #pragma unroll
    for (int j = 0; j < 2; ++j) {
      const int i = sel * 2 + j;
      int dcol = (wid + 4 * j) * 16 + r16;
      #pragma unroll
      for (int mt = 0; mt < 4; ++mt)
        #pragma unroll
        for (int rr = 0; rr < 4; ++rr)
          OB[(mt * 16 + 4 * g + rr) * 128 + dcol] = f2bf(acc[i][mt][rr] + bias[i]);
    }
    bar_lds();  // OB writes visible (LDS only; stores keep flying)
    #pragma unroll
    for (int it = 0; it < 4; ++it) {
      int flat = it * 2048 + tid * 8;
      int tokl = flat >> 7, d0 = flat & 127;
      int tg = tile * 64 + tokl;
      uint4 val = *(const uint4*)&OB[tokl * 128 + d0];
      if (sel == 0) {
        int qi = tg - 100;
        if ((unsigned)qi < 256u)
          *(uint4*)(qc + ((size_t)b * 256 + qi) * 128 + d0) = val;
      } else if (sel == 1) {
        *(uint4*)(kw + ((size_t)b * 576 + tg) * 128 + d0) = val;
      } else {
        *(uint4*)(vw + ((size_t)b * 576 + tg) * 128 + d0) = val;
      }
    }
  }
}

// ---------------- kernel 3: fused flash attention per (window, head) ----------------
// VERBATIM R7 (passing): swapped QK^T, no-max softmax, register prefetch,
// coalesced K/V staging, LDS-only barriers, no min-waves bound.
__global__ __launch_bounds__(256) void attn_kernel(
    const unsigned short* __restrict__ qc, const unsigned short* __restrict__ kw,
    const unsigned short* __restrict__ vw, unsigned short* __restrict__ ao) {
  __shared__ __align__(16) unsigned int KF[4 * 192 * 4];   // frag-major: [g][kv][pos]
  __shared__ __align__(16) unsigned short VT[32 * 200];    // [d][kv-phys] stride 200
  const int bh = blockIdx.x;
  const int tid = threadIdx.x;
  const int lane = tid & 63;
  const int wid = tid >> 6;
  const int g = lane >> 4;
  const int r16 = lane & 15;
  const int qb = wid * 64;
  const int b = bh >> 2, h = bh & 3;

  const unsigned short* qcb = qc + (size_t)b * 256 * 128 + h * 32;
  const unsigned short* kb = kw + (size_t)b * 576 * 128 + h * 32;
  const unsigned short* vb = vw + (size_t)b * 576 * 128 + h * 32;

  unsigned int kreg[12], vreg[12];
  {
    const unsigned int* ks = (const unsigned int*)kb;
    const unsigned int* vs = (const unsigned int*)vb;
    #pragma unroll
    for (int it = 0; it < 12; ++it) {
      int f = it * 256 + tid;
      int kv = f >> 4, cu = f & 15;
      kreg[it] = ks[kv * 64 + cu];
      vreg[it] = vs[kv * 64 + cu];
    }
  }

  bf16x8 qf[4];
  #pragma unroll
  for (int qnt = 0; qnt < 4; ++qnt)
    qf[qnt] = __builtin_bit_cast(bf16x8, *(const uint4*)(qcb + (size_t)(qb + qnt * 16 + r16) * 128 + g * 8));

  float ls[4];
  #pragma unroll
  for (int i = 0; i < 4; ++i) ls[i] = 0.f;
  f32x4 oa[2][4];
  #pragma unroll
  for (int i = 0; i < 2; ++i)
    #pragma unroll
    for (int j = 0; j < 4; ++j) oa[i][j] = f32x4{0.f, 0.f, 0.f, 0.f};

  const float KE = 0.17677669529663687f * 1.4426950408889634f;  // SCALE*log2(e)

  for (int ch = 0; ch < 3; ++ch) {
    if (ch) bar_lds();
    #pragma unroll
    for (int it = 0; it < 12; ++it) {
      int f = it * 256 + tid;
      int kv = f >> 4, cu = f & 15;
      KF[(cu >> 2) * 768 + kv * 4 + (cu & 3)] = kreg[it];
      int kv32 = kv & 31;
      int idx = (kv >> 5) * 32 + ((kv32 & 15) >> 2) * 8 + (kv32 >> 4) * 4 + (kv32 & 3);
      unsigned int pk = vreg[it];
      VT[(2 * cu) * 200 + idx] = (unsigned short)(pk & 0xffffu);
      VT[(2 * cu + 1) * 200 + idx] = (unsigned short)(pk >> 16);
    }
    bar_lds();
    if (ch < 2) {
      const unsigned int* ks = (const unsigned int*)(kb + (size_t)(ch + 1) * 192 * 128);
      const unsigned int* vs = (const unsigned int*)(vb + (size_t)(ch + 1) * 192 * 128);
      #pragma unroll
      for (int it = 0; it < 12; ++it) {
        int f = it * 256 + tid;
        int kv = f >> 4, cu = f & 15;
        kreg[it] = ks[kv * 64 + cu];
        vreg[it] = vs[kv * 64 + cu];
      }
    }

    for (int kvt2 = 0; kvt2 < 6; ++kvt2) {
      bf16x8 kf0 = __builtin_bit_cast(bf16x8, *(const uint4*)&KF[g * 768 + (kvt2 * 32 + r16) * 4]);
      bf16x8 kf1 = __builtin_bit_cast(bf16x8, *(const uint4*)&KF[g * 768 + (kvt2 * 32 + 16 + r16) * 4]);
      f32x4 zero = f32x4{0.f, 0.f, 0.f, 0.f};
      f32x4 st0[4], st1[4];
      #pragma unroll
      for (int qnt = 0; qnt < 4; ++qnt) {
        st0[qnt] = mfma_16x16x32(kf0, qf[qnt], zero);
        st1[qnt] = mfma_16x16x32(kf1, qf[qnt], zero);
      }

      bf16x8 pf[4];
      #pragma unroll
      for (int qnt = 0; qnt < 4; ++qnt) {
        f32x4 s0 = st0[qnt], s1 = st1[qnt];
        float p[8];
        #pragma unroll
        for (int j = 0; j < 4; ++j) p[j] = __builtin_amdgcn_exp2f(s0[j] * KE);
        #pragma unroll
        for (int j = 0; j < 4; ++j) p[4 + j] = __builtin_amdgcn_exp2f(s1[j] * KE);
        float ts = ((p[0] + p[1]) + (p[2] + p[3])) + ((p[4] + p[5]) + (p[6] + p[7]));
        ls[qnt] += ts;
        uint4 pk4;
        pk4.x = cvt_pk_bf16(p[0], p[1]);
        pk4.y = cvt_pk_bf16(p[2], p[3]);
        pk4.z = cvt_pk_bf16(p[4], p[5]);
        pk4.w = cvt_pk_bf16(p[6], p[7]);
        pf[qnt] = __builtin_bit_cast(bf16x8, pk4);
      }
      #pragma unroll
      for (int dmt = 0; dmt < 2; ++dmt) {
        int d = dmt * 16 + r16;
        bf16x8 vf = __builtin_bit_cast(bf16x8, *(const uint4*)&VT[d * 200 + kvt2 * 32 + g * 8]);
        #pragma unroll
        for (int qnt = 0; qnt < 4; ++qnt)
          oa[dmt][qnt] = mfma_16x16x32(vf, pf[qnt], oa[dmt][qnt]);
      }
    }
  }

  #pragma unroll
  for (int qnt = 0; qnt < 4; ++qnt) {
    float l = ls[qnt];
    l += __shfl_xor(l, 16);
    l += __shfl_xor(l, 32);
    float rl = 1.0f / l;
    int q = qb + qnt * 16 + r16;
    #pragma unroll
    for (int dmt = 0; dmt < 2; ++dmt) {
      #pragma unroll
      for (int rr = 0; rr < 4; ++rr) {
        int d = dmt * 16 + 4 * g + rr;
        ao[((size_t)b * 256 + q) * 128 + h * 32 + d] = f2bf(oa[dmt][qnt][rr] * rl);
      }
    }
  }
}

// ---------------- kernel 4: output projection + layout to [B,C,16,16] ----------------
__global__ __launch_bounds__(256) void proj_kernel(
    const unsigned short* __restrict__ ao, const unsigned short* __restrict__ wp,
    const float* __restrict__ proj_b, float* __restrict__ out) {
  __shared__ __align__(16) unsigned int A32[64 * 64];
  const int wg = blockIdx.x;
  const int b = wg >> 2;
  const int mq = wg & 3;
  const int tid = threadIdx.x;
  const int lane = tid & 63;
  const int wid = tid >> 6;
  const int g = lane >> 4;
  const int r16 = lane & 15;

  const unsigned int* asrc = (const unsigned int*)(ao + ((size_t)b * 256 + mq * 64) * 128);
  #pragma unroll
  for (int it = 0; it < 4; ++it) {
    int f = it * 256 + tid;
    int row = f >> 4, q4 = f & 15;
    uint4 v = *(const uint4*)&asrc[row * 64 + q4 * 4];
    *(uint4*)&A32[row * 64 + ((q4 * 4) ^ ((row & 7) << 2))] = v;
  }
  bar_lds();

  f32x4 acc[2][4];
  #pragma unroll
  for (int nt = 0; nt < 2; ++nt)
    #pragma unroll
    for (int mt = 0; mt < 4; ++mt) acc[nt][mt] = f32x4{0.f, 0.f, 0.f, 0.f};

  for (int kt = 0; kt < 4; ++kt) {
    bf16x8 afr[4];
    #pragma unroll
    for (int mt = 0; mt < 4; ++mt) {
      int row = mt * 16 + r16;
      int cub = (kt * 16 + g * 4) ^ ((row & 7) << 2);
      afr[mt] = __builtin_bit_cast(bf16x8, *(const uint4*)&A32[row * 64 + cub]);
    }
    #pragma unroll
    for (int nt = 0; nt < 2; ++nt) {
      int n = wid * 32 + nt * 16 + r16;
      bf16x8 bfr = __builtin_bit_cast(bf16x8, *(const uint4*)(wp + n * 128 + kt * 32 + g * 8));
      #pragma unroll
      for (int mt = 0; mt < 4; ++mt)
        acc[nt][mt] = mfma_16x16x32(afr[mt], bfr, acc[nt][mt]);
    }
  }

  #pragma unroll
  for (int nt = 0; nt < 2; ++nt) {
    int c = wid * 32 + nt * 16 + r16;
    float bv = proj_b[c];
    #pragma unroll
    for (int mt = 0; mt < 4; ++mt) {
      int t0 = mq * 64 + mt * 16 + 4 * g;
      float4 o;
      o.x = acc[nt][mt][0] + bv;
      o.y = acc[nt][mt][1] + bv;
      o.z = acc[nt][mt][2] + bv;
      o.w = acc[nt][mt][3] + bv;
      *(float4*)&out[((size_t)b * 128 + c) * 256 + t0] = o;
    }
  }
}

extern "C" void kernel_launch(void* const* d_in, const int* in_sizes, int n_in,
                              void* d_out, int out_size, void* d_ws, size_t ws_size,
                              hipStream_t stream) {
  const float* x = (const float*)d_in[0];
  const float* qkv_w = (const float*)d_in[1];
  const float* qkv_b = (const float*)d_in[2];
  const float* proj_w = (const float*)d_in[3];
  const float* proj_b = (const float*)d_in[4];
  float* out = (float*)d_out;

  unsigned short* ws16 = (unsigned short*)d_ws;
  unsigned short* wp = ws16;                                   // 16,384
  unsigned short* wq = ws16 + 16384;                           // 49,152
  unsigned short* xtp = ws16 + 65536;                          // 16,777,216 (xt; reused as ao)
  unsigned short* qcp = xtp + (size_t)16777216;                // 16,777,216
  unsigned short* kp = qcp + (size_t)16777216;                 // 37,748,736
  unsigned short* vp = kp + (size_t)37748736;                  // 37,748,736
  unsigned short* ap = xtp;  // alias: xt dead after qkv_kernel
  // total ws requirement: 218,234,880 B (same as R3-R7 proven budget)

  hipLaunchKernelGGL(wcvt, dim3(192), dim3(256), 0, stream, qkv_w, proj_w, wq, wp);
  hipLaunchKernelGGL(xt_kernel, dim3(512), dim3(256), 0, stream, x, xtp);
  hipLaunchKernelGGL(qkv_kernel, dim3(4608), dim3(256), 0, stream, xtp, wq, qkv_b, qcp, kp, vp);
  hipLaunchKernelGGL(attn_kernel, dim3(2048), dim3(256), 0, stream, qcp, kp, vp, ap);
  hipLaunchKernelGGL(proj_kernel, dim3(2048), dim3(256), 0, stream, ap, wp, proj_b, out);
}